// Round 7
// baseline (114.673 us; speedup 1.0000x reference)
//
#include <hip/hip_runtime.h>
#include <stdint.h>

#define NN 8192
#define KD 512
#define BM 256              // 256x256 tile
#define BK 64
#define NTILE (NN / BM)                 // 32
#define NTRI (NTILE * (NTILE + 1) / 2)  // 528
#define NKT (KD / BK)                   // 8

typedef __bf16 bf16;
typedef __bf16 bf16x8 __attribute__((ext_vector_type(8)));
typedef float f32x4 __attribute__((ext_vector_type(4)));

// ---------------- kernel 1: row L2-normalize, fp32 -> bf16 ----------------
__global__ __launch_bounds__(256) void rownorm_kernel(const float* __restrict__ proto,
                                                      bf16* __restrict__ pn) {
    const int row  = blockIdx.x * 4 + (threadIdx.x >> 6);
    const int lane = threadIdx.x & 63;
    const float4* src = (const float4*)(proto + (size_t)row * KD) + lane * 2;
    const float4 v0 = src[0];
    const float4 v1 = src[1];
    float s = v0.x*v0.x + v0.y*v0.y + v0.z*v0.z + v0.w*v0.w
            + v1.x*v1.x + v1.y*v1.y + v1.z*v1.z + v1.w*v1.w;
#pragma unroll
    for (int off = 32; off; off >>= 1) s += __shfl_xor(s, off);
    const float inv = 1.0f / fmaxf(sqrtf(s), 1e-12f);
    bf16x8 o;
    o[0] = (bf16)(v0.x*inv); o[1] = (bf16)(v0.y*inv);
    o[2] = (bf16)(v0.z*inv); o[3] = (bf16)(v0.w*inv);
    o[4] = (bf16)(v1.x*inv); o[5] = (bf16)(v1.y*inv);
    o[6] = (bf16)(v1.z*inv); o[7] = (bf16)(v1.w*inv);
    *(bf16x8*)(pn + (size_t)row * KD + lane * 8) = o;
}

// -- kernel 2: C = leakyrelu(P P^T), symmetric, 256^2 tile, 8 waves --------
// LDS layout [256 rows][64 cols] bf16 per buffer (128B rows). Swizzle:
// LDS slot (row, chunk c) holds global chunk c ^ (row&7)  (involution over
// the 8 16B-chunks of a row) -> ds_read_b128 across 16 rows = 2-way (free).
// Staged via pre-swizzled GLOBAL source col (LDS dest linear, as
// global_load_lds requires); fragment reads apply the same XOR.
__device__ __forceinline__ void gload_lds16(const bf16* g, bf16* l) {
    __builtin_amdgcn_global_load_lds(
        (const __attribute__((address_space(1))) void*)g,
        (__attribute__((address_space(3))) void*)l, 16, 0, 0);
}

__device__ __forceinline__ float lrelu(float v) {
    return (v >= 0.0f) ? v : 0.01f * v;
}

__global__ __launch_bounds__(512, 2) void gemm_sym_kernel(const bf16* __restrict__ P,
                                                          float* __restrict__ C) {
    __shared__ bf16 sA[2][BM * BK];   // 2 x 32 KB
    __shared__ bf16 sB[2][BM * BK];   // 2 x 32 KB   (total 128 KB)

    // bijective XCD swizzle: 528 = 8 x 66
    const int bid = blockIdx.x;
    const int swz = (bid & 7) * (NTRI / 8) + (bid >> 3);
    int tm = 0, rem = swz;
    while (rem >= NTILE - tm) { rem -= NTILE - tm; ++tm; }
    const int tn = tm + rem;

    const int tid  = threadIdx.x;      // 0..511
    const int w    = tid >> 6;         // wave 0..7, grid 2(M) x 4(N)
    const int lane = tid & 63;
    const int wr = w >> 2;             // 0..1 -> row offset wr*128
    const int wc = w & 3;              // 0..3 -> col offset wc*64
    const int rowA0 = tm * BM;
    const int rowB0 = tn * BM;
    const int rr = lane & 15;
    const int h  = lane >> 4;
    const int sw = rr & 7;             // read-side swizzle key

    // staging: thread -> row (tid>>3)+64*l, chunk tid&7 of each 128B row;
    // global col pre-swizzled: c ^ (row&7), (row&7)=(tid>>3)&7 for all l.
    const int swcol = ((tid & 7) ^ ((tid >> 3) & 7)) * 8;
    const bf16* gA = P + (size_t)(rowA0 + (tid >> 3)) * KD + swcol;
    const bf16* gB = P + (size_t)(rowB0 + (tid >> 3)) * KD + swcol;
    const int stL = w * 512;           // wave-uniform LDS elem offset (HW adds lane*16B)

    // fragment element offsets: row*64 + ((kkc ^ sw) << 3), kkc = kk*4 + h
    const int cA0 = ((h ^ sw) << 3);   // kk=0 chunk; kk=1 -> XOR 32 elements
    const int aBase = (wr * 128 + rr) * 64 + cA0;
    const int bBase = (wc * 64 + rr) * 64 + cA0;

    f32x4 acc[8][4] = {};

#define STAGE(buf, kt)                                                     \
    do {                                                                   \
        _Pragma("unroll")                                                  \
        for (int l = 0; l < 4; ++l) {                                      \
            gload_lds16(gA + (size_t)l * 64 * KD + (kt),                   \
                        &sA[buf][0] + l * 4096 + stL);                     \
            gload_lds16(gB + (size_t)l * 64 * KD + (kt),                   \
                        &sB[buf][0] + l * 4096 + stL);                     \
        }                                                                  \
    } while (0)

#define COMPUTE(buf)                                                        \
    do {                                                                    \
        const bf16* ra_ = &sA[buf][0];                                      \
        const bf16* rb_ = &sB[buf][0];                                      \
        bf16x8 bf_[4][2];                                                   \
        _Pragma("unroll")                                                   \
        for (int n = 0; n < 4; ++n) {                                       \
            bf_[n][0] = *(const bf16x8*)(rb_ + bBase + n * 1024);           \
            bf_[n][1] = *(const bf16x8*)(rb_ + ((bBase + n * 1024) ^ 32));  \
        }                                                                   \
        _Pragma("unroll")                                                   \
        for (int mq = 0; mq < 4; ++mq) {                                    \
            bf16x8 af_[2][2];                                               \
            _Pragma("unroll")                                               \
            for (int mi = 0; mi < 2; ++mi) {                                \
                const int ro = aBase + (mq * 2 + mi) * 1024;                \
                af_[mi][0] = *(const bf16x8*)(ra_ + ro);                    \
                af_[mi][1] = *(const bf16x8*)(ra_ + (ro ^ 32));             \
            }                                                               \
            _Pragma("unroll")                                               \
            for (int mi = 0; mi < 2; ++mi)                                  \
                _Pragma("unroll")                                           \
                for (int n = 0; n < 4; ++n) {                               \
                    acc[mq*2+mi][n] = __builtin_amdgcn_mfma_f32_16x16x32_bf16( \
                        af_[mi][0], bf_[n][0], acc[mq*2+mi][n], 0, 0, 0);   \
                    acc[mq*2+mi][n] = __builtin_amdgcn_mfma_f32_16x16x32_bf16( \
                        af_[mi][1], bf_[n][1], acc[mq*2+mi][n], 0, 0, 0);   \
                }                                                           \
        }                                                                   \
    } while (0)

    // prologue
    STAGE(0, 0);
    __syncthreads();

    // 8 K-tiles: stage t+1 into buf^1, compute t, one barrier per tile.
    // Hazards: STAGE(t+1) overwrites buf read in t-1 (barrier-protected);
    // COMPUTE(t) reads loads issued at start of t-1 (vmcnt(0) at barrier).
#pragma unroll
    for (int t = 0; t < NKT; ++t) {
        if (t < NKT - 1) STAGE((t + 1) & 1, (t + 1) * BK);
        COMPUTE(t & 1);
        if (t < NKT - 1) __syncthreads();
    }

    const int cr = h * 4;            // acc reg r -> row cr+r
    const int cc = rr;               // col

    // direct tile: C[rowA0 + wr*128 + m*16 + cr + r][rowB0 + wc*64 + n*16 + cc]
#pragma unroll
    for (int m = 0; m < 8; ++m)
#pragma unroll
        for (int n = 0; n < 4; ++n)
#pragma unroll
            for (int r = 0; r < 4; ++r)
                C[(size_t)(rowA0 + wr * 128 + m * 16 + cr + r) * NN
                  + (rowB0 + wc * 64 + n * 16 + cc)] = lrelu(acc[m][n][r]);

    // mirror tile (off-diagonal only): per-lane float4 rows of C^T
    if (tm != tn) {
#pragma unroll
        for (int m = 0; m < 8; ++m)
#pragma unroll
            for (int n = 0; n < 4; ++n) {
                float4 vv;
                vv.x = lrelu(acc[m][n][0]);
                vv.y = lrelu(acc[m][n][1]);
                vv.z = lrelu(acc[m][n][2]);
                vv.w = lrelu(acc[m][n][3]);
                *(float4*)&C[(size_t)(rowB0 + wc * 64 + n * 16 + cc) * NN
                             + (rowA0 + wr * 128 + m * 16 + cr)] = vv;
            }
    }
#undef STAGE
#undef COMPUTE
}

extern "C" void kernel_launch(void* const* d_in, const int* in_sizes, int n_in,
                              void* d_out, int out_size, void* d_ws, size_t ws_size,
                              hipStream_t stream) {
    const float* proto = (const float*)d_in[1];
    float* C  = (float*)d_out;
    bf16* pn  = (bf16*)d_ws;   // 8 MB scratch

    rownorm_kernel<<<dim3(NN / 4), dim3(256), 0, stream>>>(proto, pn);
    gemm_sym_kernel<<<dim3(NTRI), dim3(512), 0, stream>>>(pn, C);
}

// Round 8
// 109.575 us; speedup vs baseline: 1.0465x; 1.0465x over previous
//
#include <hip/hip_runtime.h>
#include <stdint.h>

#define NN 8192
#define KD 512
#define BM 256              // 256x256 tile
#define BK 32
#define NTILE (NN / BM)                 // 32
#define NTRI (NTILE * (NTILE + 1) / 2)  // 528
#define NKT (KD / BK)                   // 16

typedef __bf16 bf16;
typedef __bf16 bf16x8 __attribute__((ext_vector_type(8)));
typedef float f32x4 __attribute__((ext_vector_type(4)));

// ---------------- kernel 1: row L2-normalize, fp32 -> bf16 ----------------
__global__ __launch_bounds__(256) void rownorm_kernel(const float* __restrict__ proto,
                                                      bf16* __restrict__ pn) {
    const int row  = blockIdx.x * 4 + (threadIdx.x >> 6);
    const int lane = threadIdx.x & 63;
    const float4* src = (const float4*)(proto + (size_t)row * KD) + lane * 2;
    const float4 v0 = src[0];
    const float4 v1 = src[1];
    float s = v0.x*v0.x + v0.y*v0.y + v0.z*v0.z + v0.w*v0.w
            + v1.x*v1.x + v1.y*v1.y + v1.z*v1.z + v1.w*v1.w;
#pragma unroll
    for (int off = 32; off; off >>= 1) s += __shfl_xor(s, off);
    const float inv = 1.0f / fmaxf(sqrtf(s), 1e-12f);
    bf16x8 o;
    o[0] = (bf16)(v0.x*inv); o[1] = (bf16)(v0.y*inv);
    o[2] = (bf16)(v0.z*inv); o[3] = (bf16)(v0.w*inv);
    o[4] = (bf16)(v1.x*inv); o[5] = (bf16)(v1.y*inv);
    o[6] = (bf16)(v1.z*inv); o[7] = (bf16)(v1.w*inv);
    *(bf16x8*)(pn + (size_t)row * KD + lane * 8) = o;
}

// -- kernel 2: C = leakyrelu(P P^T), symmetric, 256^2, ring-4 pipeline -----
// LDS: 4-deep ring of K-tiles (A 16KB + B 16KB each) = 128 KB. Stage kt s+3
// while computing kt s; counted s_waitcnt vmcnt(8) (tolerates 2 K-tiles in
// flight) + raw s_barrier per kt. [256][32] row-major: each ds_read_b128
// fragment covers a full contiguous 1KB window -> bank-conflict-free.
__device__ __forceinline__ void gload_lds16(const bf16* g, bf16* l) {
    __builtin_amdgcn_global_load_lds(
        (const __attribute__((address_space(1))) void*)g,
        (__attribute__((address_space(3))) void*)l, 16, 0, 0);
}

__device__ __forceinline__ float lrelu(float v) {
    return (v >= 0.0f) ? v : 0.01f * v;
}

__global__ __launch_bounds__(512, 2) void gemm_sym_kernel(const bf16* __restrict__ P,
                                                          float* __restrict__ C) {
    __shared__ bf16 sm[4][2][BM * BK];   // [ring][A=0/B=1][256*32] = 128 KB

    // bijective XCD swizzle: 528 = 8 x 66
    const int bid = blockIdx.x;
    const int swz = (bid & 7) * (NTRI / 8) + (bid >> 3);
    int tm = 0, rem = swz;
    while (rem >= NTILE - tm) { rem -= NTILE - tm; ++tm; }
    const int tn = tm + rem;

    const int tid  = threadIdx.x;      // 0..511
    const int w    = tid >> 6;         // wave 0..7, grid 2(M) x 4(N)
    const int lane = tid & 63;
    const int wr = w >> 2;             // row offset wr*128
    const int wc = w & 3;              // col offset wc*64
    const int rowA0 = tm * BM;
    const int rowB0 = tn * BM;
    const int rr = lane & 15;
    const int h  = lane >> 4;

    // staging: thread covers rows (tid>>2) and (tid>>2)+128, chunk tid&3
    const bf16* gA = P + (size_t)(rowA0 + (tid >> 2)) * KD + (tid & 3) * 8;
    const bf16* gB = P + (size_t)(rowB0 + (tid >> 2)) * KD + (tid & 3) * 8;
    const int stL = w * 512;           // wave-uniform LDS elem base (HW adds lane*16B)

    // fragment element offsets
    const int aBase = (wr * 128 + rr) * BK + h * 8;
    const int bBase = (wc * 64  + rr) * BK + h * 8;

    f32x4 acc[8][4] = {};

#define VMCNT(n) asm volatile("s_waitcnt vmcnt(" #n ")" ::: "memory")

#define STAGE(s_)                                                       \
    do {                                                                \
        bf16* a_ = &sm[(s_) & 3][0][0];                                 \
        bf16* b_ = &sm[(s_) & 3][1][0];                                 \
        const int kt_ = (s_) * BK;                                      \
        gload_lds16(gA + kt_,            a_ + stL);                     \
        gload_lds16(gA + 128 * KD + kt_, a_ + stL + 4096);              \
        gload_lds16(gB + kt_,            b_ + stL);                     \
        gload_lds16(gB + 128 * KD + kt_, b_ + stL + 4096);              \
    } while (0)

#define COMPUTE(s_)                                                         \
    do {                                                                    \
        const bf16* ra_ = &sm[(s_) & 3][0][0];                              \
        const bf16* rb_ = &sm[(s_) & 3][1][0];                              \
        bf16x8 af[8], bfr[4];                                               \
        _Pragma("unroll")                                                   \
        for (int m = 0; m < 8; ++m)                                         \
            af[m] = *(const bf16x8*)(ra_ + aBase + m * 512);                \
        _Pragma("unroll")                                                   \
        for (int n = 0; n < 4; ++n)                                         \
            bfr[n] = *(const bf16x8*)(rb_ + bBase + n * 512);               \
        __builtin_amdgcn_s_setprio(1);                                      \
        _Pragma("unroll")                                                   \
        for (int m = 0; m < 8; ++m)                                         \
            _Pragma("unroll")                                               \
            for (int n = 0; n < 4; ++n)                                     \
                acc[m][n] = __builtin_amdgcn_mfma_f32_16x16x32_bf16(        \
                    af[m], bfr[n], acc[m][n], 0, 0, 0);                     \
        __builtin_amdgcn_s_setprio(0);                                      \
    } while (0)

    // prologue: 3 K-tiles in flight (12 loads)
    STAGE(0); STAGE(1); STAGE(2);

    // ledger: at kt s entry, outstanding <= {s..s+3} (16); vmcnt(8) retires
    // {s, s+1} -> kt s landed for ALL waves before the barrier. stage(s+3)
    // targets buf[(s+3)&3] == buf[(s-1)&3], whose readers retired before the
    // previous trailing barrier. Tail: s=14 -> vmcnt(4), s=15 -> vmcnt(0).
#pragma unroll
    for (int s = 0; s < NKT; ++s) {
        if (s + 3 < NKT) STAGE(s + 3);
        if (s <= NKT - 3) VMCNT(8);
        else if (s == NKT - 2) VMCNT(4);
        else VMCNT(0);
        __builtin_amdgcn_s_barrier();
        COMPUTE(s);
        if (s < NKT - 1) __builtin_amdgcn_s_barrier();
    }
#undef STAGE
#undef COMPUTE
#undef VMCNT

    const int cr = h * 4;            // acc reg r -> row cr+r
    const int cc = rr;               // col

    // direct tile: C[rowA0 + wr*128 + m*16 + cr + r][rowB0 + wc*64 + n*16 + cc]
#pragma unroll
    for (int m = 0; m < 8; ++m)
#pragma unroll
        for (int n = 0; n < 4; ++n)
#pragma unroll
            for (int r = 0; r < 4; ++r)
                C[(size_t)(rowA0 + wr * 128 + m * 16 + cr + r) * NN
                  + (rowB0 + wc * 64 + n * 16 + cc)] = lrelu(acc[m][n][r]);

    // mirror tile (off-diagonal only): per-lane float4 rows of C^T
    if (tm != tn) {
#pragma unroll
        for (int m = 0; m < 8; ++m)
#pragma unroll
            for (int n = 0; n < 4; ++n) {
                float4 vv;
                vv.x = lrelu(acc[m][n][0]);
                vv.y = lrelu(acc[m][n][1]);
                vv.z = lrelu(acc[m][n][2]);
                vv.w = lrelu(acc[m][n][3]);
                *(float4*)&C[(size_t)(rowB0 + wc * 64 + n * 16 + cc) * NN
                             + (rowA0 + wr * 128 + m * 16 + cr)] = vv;
            }
    }
}

extern "C" void kernel_launch(void* const* d_in, const int* in_sizes, int n_in,
                              void* d_out, int out_size, void* d_ws, size_t ws_size,
                              hipStream_t stream) {
    const float* proto = (const float*)d_in[1];
    float* C  = (float*)d_out;
    bf16* pn  = (bf16*)d_ws;   // 8 MB scratch

    rownorm_kernel<<<dim3(NN / 4), dim3(256), 0, stream>>>(proto, pn);
    gemm_sym_kernel<<<dim3(NTRI), dim3(512), 0, stream>>>(pn, C);
}

// Round 9
// 94.623 us; speedup vs baseline: 1.2119x; 1.1580x over previous
//
#include <hip/hip_runtime.h>
#include <stdint.h>

#define NN 8192
#define KD 512
#define BM 128
#define BK 32
#define NTILE (NN / BM)                 // 64
#define NTRI (NTILE * (NTILE + 1) / 2)  // 2080
#define NKT (KD / BK)                   // 16

typedef __bf16 bf16;
typedef __bf16 bf16x8 __attribute__((ext_vector_type(8)));
typedef float f32x4 __attribute__((ext_vector_type(4)));

// ---------------- kernel 1: row L2-normalize, fp32 -> bf16 ----------------
__global__ __launch_bounds__(256) void rownorm_kernel(const float* __restrict__ proto,
                                                      bf16* __restrict__ pn) {
    const int row  = blockIdx.x * 4 + (threadIdx.x >> 6);
    const int lane = threadIdx.x & 63;
    const float4* src = (const float4*)(proto + (size_t)row * KD) + lane * 2;
    const float4 v0 = src[0];
    const float4 v1 = src[1];
    float s = v0.x*v0.x + v0.y*v0.y + v0.z*v0.z + v0.w*v0.w
            + v1.x*v1.x + v1.y*v1.y + v1.z*v1.z + v1.w*v1.w;
#pragma unroll
    for (int off = 32; off; off >>= 1) s += __shfl_xor(s, off);
    const float inv = 1.0f / fmaxf(sqrtf(s), 1e-12f);
    bf16x8 o;
    o[0] = (bf16)(v0.x*inv); o[1] = (bf16)(v0.y*inv);
    o[2] = (bf16)(v0.z*inv); o[3] = (bf16)(v0.w*inv);
    o[4] = (bf16)(v1.x*inv); o[5] = (bf16)(v1.y*inv);
    o[6] = (bf16)(v1.z*inv); o[7] = (bf16)(v1.w*inv);
    *(bf16x8*)(pn + (size_t)row * KD + lane * 8) = o;
}

// -- kernel 2: C = leakyrelu(P P^T), symmetric, LDS-staged full-line writes -
__device__ __forceinline__ void gload_lds16(const bf16* g, bf16* l) {
    __builtin_amdgcn_global_load_lds(
        (const __attribute__((address_space(1))) void*)g,
        (__attribute__((address_space(3))) void*)l, 16, 0, 0);
}

__device__ __forceinline__ float lrelu(float v) {
    return (v >= 0.0f) ? v : 0.01f * v;
}

__global__ __launch_bounds__(256, 4) void gemm_sym_kernel(const bf16* __restrict__ P,
                                                          float* __restrict__ C) {
    // overlay: K-loop staging (32 KB) and epilogue buffer [64][129] f32 (33 KB)
    __shared__ __align__(16) unsigned char smem[33024];
    bf16*  sA = (bf16*)smem;               // [2][4096] elems
    bf16*  sB = (bf16*)(smem + 16384);     // [2][4096] elems
    float* sE = (float*)smem;              // [64][129]

    // bijective XCD swizzle: 2080 = 8 x 260
    const int bid = blockIdx.x;
    const int swz = (bid & 7) * (NTRI / 8) + (bid >> 3);
    int tm = 0, rem = swz;
    while (rem >= NTILE - tm) { rem -= NTILE - tm; ++tm; }
    const int tn = tm + rem;

    const int tid  = threadIdx.x;
    const int w    = tid >> 6;
    const int lane = tid & 63;
    const int wr = w >> 1;               // wave row 0..1 -> rows wr*64..+63
    const int rowA0 = tm * BM;
    const int rowB0 = tn * BM;
    const int wm = wr * 64;
    const int wn = (w & 1) * 64;
    const int rr = lane & 15;
    const int h  = lane >> 4;

    // staging: wave w covers rows w*32..w*32+31 (two 16-row slots)
    const int chunk0 = w * 128 + lane;
    const bf16* g0 = P + (size_t)(chunk0 >> 2) * KD + (chunk0 & 3) * 8;
    const size_t offA = (size_t)rowA0 * KD;
    const size_t offB = (size_t)rowB0 * KD;
    const int ldsOff0 = w * 1024;
    const int ldsOff1 = w * 1024 + 512;

    f32x4 acc[4][4] = {};

#define STAGE(buf, kt)                                                        \
    do {                                                                      \
        gload_lds16(g0 + offA + (kt),           sA + (buf) * 4096 + ldsOff0); \
        gload_lds16(g0 + offA + 16 * KD + (kt), sA + (buf) * 4096 + ldsOff1); \
        gload_lds16(g0 + offB + (kt),           sB + (buf) * 4096 + ldsOff0); \
        gload_lds16(g0 + offB + 16 * KD + (kt), sB + (buf) * 4096 + ldsOff1); \
    } while (0)

#define COMPUTE(buf)                                                          \
    do {                                                                      \
        const bf16* ra_ = sA + (buf) * 4096;                                  \
        const bf16* rb_ = sB + (buf) * 4096;                                  \
        bf16x8 af[4], bfr[4];                                                 \
        _Pragma("unroll")                                                     \
        for (int m = 0; m < 4; ++m)                                           \
            af[m] = *(const bf16x8*)(ra_ + (wm + m * 16 + rr) * 32 + h * 8);  \
        _Pragma("unroll")                                                     \
        for (int n = 0; n < 4; ++n)                                           \
            bfr[n] = *(const bf16x8*)(rb_ + (wn + n * 16 + rr) * 32 + h * 8); \
        _Pragma("unroll")                                                     \
        for (int m = 0; m < 4; ++m)                                           \
            _Pragma("unroll")                                                 \
            for (int n = 0; n < 4; ++n)                                       \
                acc[m][n] = __builtin_amdgcn_mfma_f32_16x16x32_bf16(          \
                    af[m], bfr[n], acc[m][n], 0, 0, 0);                       \
    } while (0)

    // prologue: tile 0 -> buf 0
    STAGE(0, 0);
    __syncthreads();

    // dbuf: stage t+1, compute t, one barrier per K-tile (R4 structure)
#pragma unroll
    for (int t = 0; t < NKT; ++t) {
        if (t < NKT - 1) STAGE((t + 1) & 1, (t + 1) * BK);
        COMPUTE(t & 1);
        if (t < NKT - 1) __syncthreads();
    }

    // ---- LDS-staged epilogue: two 64-row halves, full-line stores ----
    const int cr = h * 4;            // acc reg r -> local row cr+r
    const int cc = rr;               // local col within wave's 64-col strip

#pragma unroll
    for (int H = 0; H < 2; ++H) {
        __syncthreads();   // K-loop reads done (H=0) / prev half reads done (H=1)
        if (wr == H) {
#pragma unroll
            for (int m = 0; m < 4; ++m)
#pragma unroll
                for (int n = 0; n < 4; ++n)
#pragma unroll
                    for (int r = 0; r < 4; ++r)
                        sE[(m * 16 + cr + r) * 129 + wn + n * 16 + cc] =
                            lrelu(acc[m][n][r]);
        }
        __syncthreads();

        // direct: rows rowA0+H*64+lr, 128 cols; 32 lanes = 512B/row (4 lines)
#pragma unroll
        for (int k = 0; k < 8; ++k) {
            const int seg = tid + k * 256;
            const int lr  = seg >> 5;
            const int c4  = (seg & 31) * 4;
            const float4 v = *(const float4*)&sE[lr * 129 + c4];
            *(float4*)&C[(size_t)(rowA0 + H * 64 + lr) * NN + rowB0 + c4] = v;
        }

        // mirror (off-diag): row j = tile col; transposed LDS read (2-way banks)
        if (tm != tn) {
#pragma unroll
            for (int rd = 0; rd < 8; ++rd) {
                const int j = (tid >> 4) + rd * 16;
                const int i0 = (tid & 15) * 4;
                float4 v;
                v.x = sE[(i0 + 0) * 129 + j];
                v.y = sE[(i0 + 1) * 129 + j];
                v.z = sE[(i0 + 2) * 129 + j];
                v.w = sE[(i0 + 3) * 129 + j];
                *(float4*)&C[(size_t)(rowB0 + j) * NN + rowA0 + H * 64 + i0] = v;
            }
        }
    }
#undef STAGE
#undef COMPUTE
}

extern "C" void kernel_launch(void* const* d_in, const int* in_sizes, int n_in,
                              void* d_out, int out_size, void* d_ws, size_t ws_size,
                              hipStream_t stream) {
    const float* proto = (const float*)d_in[1];
    float* C  = (float*)d_out;
    bf16* pn  = (bf16*)d_ws;   // 8 MB scratch

    rownorm_kernel<<<dim3(NN / 4), dim3(256), 0, stream>>>(proto, pn);
    gemm_sym_kernel<<<dim3(NTRI), dim3(256), 0, stream>>>(pn, C);
}